// Round 1
// baseline (420.457 us; speedup 1.0000x reference)
//
#include <hip/hip_runtime.h>

typedef __bf16 bf16_t;
typedef __bf16 bf16x8 __attribute__((ext_vector_type(8)));
typedef __bf16 bf16x4 __attribute__((ext_vector_type(4)));
typedef float f32x4 __attribute__((ext_vector_type(4)));

static __device__ __forceinline__ f32x4 mfma16(bf16x8 a, bf16x8 b, f32x4 c) {
    return __builtin_amdgcn_mfma_f32_16x16x32_bf16(a, b, c, 0, 0, 0);
}

constexpr int B_ = 2, S_ = 2048, H_ = 16, DH = 128, AF = 2048;
constexpr int M_ = B_ * S_;  // 4096

// ---------------- f32 -> bf16 convert (query) ----------------
__global__ void cvt_f32_to_bf16(const float* __restrict__ in, bf16_t* __restrict__ out) {
    int i = (blockIdx.x * 256 + threadIdx.x) * 4;
    const float4 v = *reinterpret_cast<const float4*>(in + i);
    bf16x4 o = { (bf16_t)v.x, (bf16_t)v.y, (bf16_t)v.z, (bf16_t)v.w };
    *reinterpret_cast<bf16x4*>(out + i) = o;
}

// ---------------- f32 [R][C] -> bf16 [C][R] transpose ----------------
__global__ void transpose_to_bf16(const float* __restrict__ in, bf16_t* __restrict__ out,
                                  int R, int C) {
    __shared__ float t[32][33];
    int c0 = blockIdx.x * 32, r0 = blockIdx.y * 32;
    int tx = threadIdx.x & 31, ty = threadIdx.x >> 5;  // 32 x 8
#pragma unroll
    for (int i = 0; i < 4; i++) t[ty + i * 8][tx] = in[(size_t)(r0 + ty + i * 8) * C + c0 + tx];
    __syncthreads();
#pragma unroll
    for (int i = 0; i < 4; i++)
        out[(size_t)(c0 + ty + i * 8) * R + r0 + tx] = (bf16_t)t[tx][ty + i * 8];
}

// ---------------- 128x128-tile bf16 GEMM: C = A[M][K] * Bt[N][K]^T + bias ----------------
// 4 waves (2x2), each wave 64x64 (4x4 frags of 16x16x32). BK=64, XOR-swizzled LDS.
template <int K, int N, bool OUTBF16, bool QKV>
__global__ __launch_bounds__(256) void gemm128(
    const bf16_t* __restrict__ A, const bf16_t* __restrict__ Bt,
    const float* __restrict__ b0, const float* __restrict__ b1, const float* __restrict__ b2,
    bf16_t* __restrict__ Cqk, bf16_t* __restrict__ Vt, float* __restrict__ Cf) {
    __shared__ bf16_t As[128 * 64];
    __shared__ bf16_t Bs[128 * 64];
    const int z = blockIdx.z;
    const bf16_t* Bz = Bt + (size_t)z * N * K;
    const float* bias = (z == 0) ? b0 : (z == 1 ? b1 : b2);
    const int m0 = blockIdx.y * 128, n0 = blockIdx.x * 128;
    const int tid = threadIdx.x, lane = tid & 63, wave = tid >> 6;
    const int wm = (wave >> 1) * 64, wn = (wave & 1) * 64;
    const int fr = lane & 15, fq = lane >> 4;

    f32x4 acc[4][4];
    const f32x4 fz = {0.f, 0.f, 0.f, 0.f};
#pragma unroll
    for (int i = 0; i < 4; i++)
#pragma unroll
        for (int j = 0; j < 4; j++) acc[i][j] = fz;

    for (int kt = 0; kt < K / 64; ++kt) {
        const int k0 = kt * 64;
        bf16x8 ar[4], br[4];
#pragma unroll
        for (int j = 0; j < 4; j++) {
            int cid = tid + 256 * j;           // 16B chunk id, 0..1023
            int r = cid >> 3;                  // tile row 0..127
            int sc = ((cid & 7) ^ (r & 7)) << 3;  // swizzled source col (elements)
            ar[j] = *reinterpret_cast<const bf16x8*>(A + (size_t)(m0 + r) * K + k0 + sc);
            br[j] = *reinterpret_cast<const bf16x8*>(Bz + (size_t)(n0 + r) * K + k0 + sc);
        }
#pragma unroll
        for (int j = 0; j < 4; j++) {
            int cid = tid + 256 * j;
            *reinterpret_cast<bf16x8*>(reinterpret_cast<char*>(As) + cid * 16) = ar[j];
            *reinterpret_cast<bf16x8*>(reinterpret_cast<char*>(Bs) + cid * 16) = br[j];
        }
        __syncthreads();
#pragma unroll
        for (int ks = 0; ks < 2; ++ks) {
            bf16x8 af[4], bfv[4];
#pragma unroll
            for (int mi = 0; mi < 4; mi++) {
                int r = wm + mi * 16 + fr;
                int cb = (ks * 64 + fq * 16) ^ ((r & 7) << 4);
                af[mi] = *reinterpret_cast<const bf16x8*>(reinterpret_cast<const char*>(As) + r * 128 + cb);
            }
#pragma unroll
            for (int ni = 0; ni < 4; ni++) {
                int r = wn + ni * 16 + fr;
                int cb = (ks * 64 + fq * 16) ^ ((r & 7) << 4);
                bfv[ni] = *reinterpret_cast<const bf16x8*>(reinterpret_cast<const char*>(Bs) + r * 128 + cb);
            }
#pragma unroll
            for (int mi = 0; mi < 4; mi++)
#pragma unroll
                for (int ni = 0; ni < 4; ni++) acc[mi][ni] = mfma16(af[mi], bfv[ni], acc[mi][ni]);
        }
        __syncthreads();
    }

    // epilogue: C/D layout col = lane&15, row = (lane>>4)*4 + reg   [m89]
#pragma unroll
    for (int ni = 0; ni < 4; ni++) {
        const int col = n0 + wn + ni * 16 + fr;
        const float bb = bias[col];
#pragma unroll
        for (int mi = 0; mi < 4; mi++) {
            const int mrow = m0 + wm + mi * 16 + fq * 4;
            f32x4 v = acc[mi][ni];
            if (OUTBF16) {
                if (QKV && z == 2) {
                    // write V directly transposed: Vt[b][h][d][s]
                    const int b = mrow >> 11, s = mrow & (S_ - 1);
                    const int h = col >> 7, d = col & (DH - 1);
                    bf16x4 w = { (bf16_t)(v[0] + bb), (bf16_t)(v[1] + bb),
                                 (bf16_t)(v[2] + bb), (bf16_t)(v[3] + bb) };
                    *reinterpret_cast<bf16x4*>(Vt + ((size_t)((b * H_ + h) * DH + d)) * S_ + s) = w;
                } else {
                    bf16_t* Cz = Cqk + (size_t)z * M_ * N;
#pragma unroll
                    for (int j = 0; j < 4; j++)
                        Cz[(size_t)(mrow + j) * N + col] = (bf16_t)(v[j] + bb);
                }
            } else {
#pragma unroll
                for (int j = 0; j < 4; j++) Cf[(size_t)(mrow + j) * N + col] = v[j] + bb;
            }
        }
    }
}

// ---------------- causal flash attention ----------------
// grid (B*H, S/64), 4 waves/block; each wave owns 16 q-rows.
// K/V read straight from global (L2-resident, 512KB/head); only P goes via LDS (wave-private).
__global__ __launch_bounds__(256) void attn(
    const bf16_t* __restrict__ Q, const bf16_t* __restrict__ Kc,
    const bf16_t* __restrict__ Vt, bf16_t* __restrict__ Ctx) {
    const int bh = blockIdx.x, b = bh >> 4, h = bh & 15;
    const int qt = blockIdx.y;
    const int lane = threadIdx.x & 63, wave = threadIdx.x >> 6;
    const int fr = lane & 15, fq = lane >> 4;
    const int qrow0 = qt * 64 + wave * 16;

    __shared__ bf16_t Pl[4][16][72];

    bf16x8 qf[4];
    {
        const bf16_t* qp = Q + ((size_t)(b * S_ + qrow0 + fr)) * AF + h * DH + fq * 8;
#pragma unroll
        for (int ds = 0; ds < 4; ++ds) qf[ds] = *reinterpret_cast<const bf16x8*>(qp + ds * 32);
    }
    float m_[4], l_[4];
    f32x4 o[8];
    const f32x4 fz = {0.f, 0.f, 0.f, 0.f};
#pragma unroll
    for (int r = 0; r < 4; r++) { m_[r] = -3.0e38f; l_[r] = 0.f; }
#pragma unroll
    for (int d = 0; d < 8; d++) o[d] = fz;

    const float scale = 0.022097086912079608f;  // 1/sqrt(2048)
    const bf16_t* kp0 = Kc + ((size_t)(b * S_ + fr)) * AF + h * DH + fq * 8;
    const bf16_t* vp0 = Vt + (size_t)bh * DH * S_ + fq * 8;

    for (int kvt = 0; kvt <= qt; ++kvt) {
        const int kv0 = kvt * 64;
        f32x4 sv[4];
#pragma unroll
        for (int kvf = 0; kvf < 4; ++kvf) {
            f32x4 a = fz;
            const bf16_t* kp = kp0 + (size_t)(kv0 + kvf * 16) * AF;
#pragma unroll
            for (int ds = 0; ds < 4; ++ds)
                a = mfma16(qf[ds], *reinterpret_cast<const bf16x8*>(kp + ds * 32), a);
            sv[kvf] = a;
        }
        const bool diag = (kvt == qt);
        float p[4][4];
#pragma unroll
        for (int r = 0; r < 4; r++) {
            const int qrow = qrow0 + fq * 4 + r;
            float mx = -3.0e38f;
            float x[4];
#pragma unroll
            for (int kvf = 0; kvf < 4; kvf++) {
                float t = sv[kvf][r] * scale;
                if (diag && (kv0 + kvf * 16 + fr > qrow)) t = -3.0e38f;
                x[kvf] = t;
                mx = fmaxf(mx, t);
            }
#pragma unroll
            for (int off = 1; off < 16; off <<= 1) mx = fmaxf(mx, __shfl_xor(mx, off, 64));
            const float mnew = fmaxf(m_[r], mx);
            const float corr = __expf(m_[r] - mnew);
            float rs = 0.f;
#pragma unroll
            for (int kvf = 0; kvf < 4; kvf++) {
                float e = __expf(x[kvf] - mnew);
                p[r][kvf] = e;
                rs += e;
            }
#pragma unroll
            for (int off = 1; off < 16; off <<= 1) rs += __shfl_xor(rs, off, 64);
            l_[r] = l_[r] * corr + rs;
            m_[r] = mnew;
#pragma unroll
            for (int d = 0; d < 8; d++) o[d][r] *= corr;
        }
        // P -> wave-private LDS (DS ops are in-order within a wave)
#pragma unroll
        for (int r = 0; r < 4; r++)
#pragma unroll
            for (int kvf = 0; kvf < 4; kvf++)
                Pl[wave][fq * 4 + r][kvf * 16 + fr] = (bf16_t)p[r][kvf];
        // PV
#pragma unroll
        for (int ks = 0; ks < 2; ks++) {
            const bf16x8 pf = *reinterpret_cast<const bf16x8*>(&Pl[wave][fr][ks * 32 + fq * 8]);
            const bf16_t* vp = vp0 + kv0 + ks * 32;
#pragma unroll
            for (int d = 0; d < 8; d++) {
                const bf16x8 vf = *reinterpret_cast<const bf16x8*>(vp + (size_t)(d * 16 + fr) * S_);
                o[d] = mfma16(pf, vf, o[d]);
            }
        }
    }
#pragma unroll
    for (int r = 0; r < 4; r++) l_[r] = 1.0f / l_[r];
#pragma unroll
    for (int d = 0; d < 8; d++) {
#pragma unroll
        for (int r = 0; r < 4; r++) {
            const size_t row = (size_t)(b * S_ + qrow0 + fq * 4 + r);
            Ctx[row * AF + h * DH + d * 16 + fr] = (bf16_t)(o[d][r] * l_[r]);
        }
    }
}

extern "C" void kernel_launch(void* const* d_in, const int* in_sizes, int n_in,
                              void* d_out, int out_size, void* d_ws, size_t ws_size,
                              hipStream_t stream) {
    const float* query = (const float*)d_in[0];
    const float* Wq = (const float*)d_in[1];
    const float* bq = (const float*)d_in[2];
    const float* Wk = (const float*)d_in[3];
    const float* bk = (const float*)d_in[4];
    const float* Wv = (const float*)d_in[5];
    const float* bv = (const float*)d_in[6];
    const float* Wo = (const float*)d_in[7];
    const float* bo = (const float*)d_in[8];
    float* out = (float*)d_out;
    char* ws = (char*)d_ws;

    // workspace layout (bytes). ctx reuses the x/Wt_qkv region after they are dead.
    bf16_t* xbf  = (bf16_t*)(ws + 0);          // [4096][1024]            8,388,608
    bf16_t* wtq  = (bf16_t*)(ws + 8388608);    // [3][2048][1024]        12,582,912
    bf16_t* wto  = (bf16_t*)(ws + 20971520);   // [1024][2048]            4,194,304
    bf16_t* qws  = (bf16_t*)(ws + 25165824);   // Q [4096][2048], K follows at z-stride
    bf16_t* vtws = (bf16_t*)(ws + 58720256);   // Vt [32][128][2048]     16,777,216
    bf16_t* ctx  = (bf16_t*)(ws + 0);          // [4096][2048] (aliases xbf/wtq)

    cvt_f32_to_bf16<<<4096, 256, 0, stream>>>(query, xbf);
    transpose_to_bf16<<<dim3(64, 32), 256, 0, stream>>>(Wq, wtq, 1024, 2048);
    transpose_to_bf16<<<dim3(64, 32), 256, 0, stream>>>(Wk, wtq + 2097152, 1024, 2048);
    transpose_to_bf16<<<dim3(64, 32), 256, 0, stream>>>(Wv, wtq + 2 * 2097152, 1024, 2048);
    transpose_to_bf16<<<dim3(32, 64), 256, 0, stream>>>(Wo, wto, 2048, 1024);

    gemm128<1024, 2048, true, true><<<dim3(16, 32, 3), 256, 0, stream>>>(
        xbf, wtq, bq, bk, bv, qws, vtws, nullptr);

    attn<<<dim3(32, 32), 256, 0, stream>>>(qws, qws + (size_t)4096 * 2048, vtws, ctx);

    gemm128<2048, 1024, false, false><<<dim3(8, 32, 1), 256, 0, stream>>>(
        ctx, wto, bo, bo, bo, nullptr, nullptr, out);
}

// Round 3
// 231.415 us; speedup vs baseline: 1.8169x; 1.8169x over previous
//
#include <hip/hip_runtime.h>

typedef __bf16 bf16_t;
typedef __bf16 bf16x8 __attribute__((ext_vector_type(8)));
typedef __bf16 bf16x4 __attribute__((ext_vector_type(4)));
typedef float f32x4 __attribute__((ext_vector_type(4)));

static __device__ __forceinline__ f32x4 mfma16(bf16x8 a, bf16x8 b, f32x4 c) {
    return __builtin_amdgcn_mfma_f32_16x16x32_bf16(a, b, c, 0, 0, 0);
}

#define AS1 __attribute__((address_space(1)))
#define AS3 __attribute__((address_space(3)))
static __device__ __forceinline__ void gload16(const void* g, void* l) {
    __builtin_amdgcn_global_load_lds((AS1 const void*)g, (AS3 void*)l, 16, 0, 0);
}

constexpr int B_ = 2, S_ = 2048, H_ = 16, DH = 128, AF = 2048;
constexpr int M_ = B_ * S_;  // 4096

// ---------------- f32 -> bf16 convert (query) ----------------
__global__ void cvt_f32_to_bf16(const float* __restrict__ in, bf16_t* __restrict__ out) {
    int i = (blockIdx.x * 256 + threadIdx.x) * 4;
    const float4 v = *reinterpret_cast<const float4*>(in + i);
    bf16x4 o = { (bf16_t)v.x, (bf16_t)v.y, (bf16_t)v.z, (bf16_t)v.w };
    *reinterpret_cast<bf16x4*>(out + i) = o;
}

// ---------------- f32 [R][C] -> bf16 [C][R] transpose ----------------
__global__ void transpose_to_bf16(const float* __restrict__ in, bf16_t* __restrict__ out,
                                  int R, int C) {
    __shared__ float t[32][33];
    int c0 = blockIdx.x * 32, r0 = blockIdx.y * 32;
    int tx = threadIdx.x & 31, ty = threadIdx.x >> 5;  // 32 x 8
#pragma unroll
    for (int i = 0; i < 4; i++) t[ty + i * 8][tx] = in[(size_t)(r0 + ty + i * 8) * C + c0 + tx];
    __syncthreads();
#pragma unroll
    for (int i = 0; i < 4; i++)
        out[(size_t)(c0 + ty + i * 8) * R + r0 + tx] = (bf16_t)t[tx][ty + i * 8];
}

// ---------------- 128x128-tile bf16 GEMM: C = A[M][K] * Bt[N][K]^T + bias ----------------
template <int K, int N, bool OUTBF16, bool QKV>
__global__ __launch_bounds__(256) void gemm128(
    const bf16_t* __restrict__ A, const bf16_t* __restrict__ Bt,
    const float* __restrict__ b0, const float* __restrict__ b1, const float* __restrict__ b2,
    bf16_t* __restrict__ Cqk, bf16_t* __restrict__ Vt, float* __restrict__ Cf) {
    __shared__ bf16_t As[128 * 64];
    __shared__ bf16_t Bs[128 * 64];
    const int z = blockIdx.z;
    const bf16_t* Bz = Bt + (size_t)z * N * K;
    const float* bias = (z == 0) ? b0 : (z == 1 ? b1 : b2);
    const int m0 = blockIdx.y * 128, n0 = blockIdx.x * 128;
    const int tid = threadIdx.x, lane = tid & 63, wave = tid >> 6;
    const int wm = (wave >> 1) * 64, wn = (wave & 1) * 64;
    const int fr = lane & 15, fq = lane >> 4;

    f32x4 acc[4][4];
    const f32x4 fz = {0.f, 0.f, 0.f, 0.f};
#pragma unroll
    for (int i = 0; i < 4; i++)
#pragma unroll
        for (int j = 0; j < 4; j++) acc[i][j] = fz;

    for (int kt = 0; kt < K / 64; ++kt) {
        const int k0 = kt * 64;
        bf16x8 ar[4], br[4];
#pragma unroll
        for (int j = 0; j < 4; j++) {
            int cid = tid + 256 * j;
            int r = cid >> 3;
            int sc = ((cid & 7) ^ (r & 7)) << 3;
            ar[j] = *reinterpret_cast<const bf16x8*>(A + (size_t)(m0 + r) * K + k0 + sc);
            br[j] = *reinterpret_cast<const bf16x8*>(Bz + (size_t)(n0 + r) * K + k0 + sc);
        }
#pragma unroll
        for (int j = 0; j < 4; j++) {
            int cid = tid + 256 * j;
            *reinterpret_cast<bf16x8*>(reinterpret_cast<char*>(As) + cid * 16) = ar[j];
            *reinterpret_cast<bf16x8*>(reinterpret_cast<char*>(Bs) + cid * 16) = br[j];
        }
        __syncthreads();
#pragma unroll
        for (int ks = 0; ks < 2; ++ks) {
            bf16x8 af[4], bfv[4];
#pragma unroll
            for (int mi = 0; mi < 4; mi++) {
                int r = wm + mi * 16 + fr;
                int cb = (ks * 64 + fq * 16) ^ ((r & 7) << 4);
                af[mi] = *reinterpret_cast<const bf16x8*>(reinterpret_cast<const char*>(As) + r * 128 + cb);
            }
#pragma unroll
            for (int ni = 0; ni < 4; ni++) {
                int r = wn + ni * 16 + fr;
                int cb = (ks * 64 + fq * 16) ^ ((r & 7) << 4);
                bfv[ni] = *reinterpret_cast<const bf16x8*>(reinterpret_cast<const char*>(Bs) + r * 128 + cb);
            }
#pragma unroll
            for (int mi = 0; mi < 4; mi++)
#pragma unroll
                for (int ni = 0; ni < 4; ni++) acc[mi][ni] = mfma16(af[mi], bfv[ni], acc[mi][ni]);
        }
        __syncthreads();
    }

#pragma unroll
    for (int ni = 0; ni < 4; ni++) {
        const int col = n0 + wn + ni * 16 + fr;
        const float bb = bias[col];
#pragma unroll
        for (int mi = 0; mi < 4; mi++) {
            const int mrow = m0 + wm + mi * 16 + fq * 4;
            f32x4 v = acc[mi][ni];
            if (OUTBF16) {
                if (QKV && z == 2) {
                    const int b = mrow >> 11, s = mrow & (S_ - 1);
                    const int h = col >> 7, d = col & (DH - 1);
                    bf16x4 w = { (bf16_t)(v[0] + bb), (bf16_t)(v[1] + bb),
                                 (bf16_t)(v[2] + bb), (bf16_t)(v[3] + bb) };
                    *reinterpret_cast<bf16x4*>(Vt + ((size_t)((b * H_ + h) * DH + d)) * S_ + s) = w;
                } else {
                    bf16_t* Cz = Cqk + (size_t)z * M_ * N;
#pragma unroll
                    for (int j = 0; j < 4; j++)
                        Cz[(size_t)(mrow + j) * N + col] = (bf16_t)(v[j] + bb);
                }
            } else {
#pragma unroll
                for (int j = 0; j < 4; j++) Cf[(size_t)(mrow + j) * N + col] = v[j] + bb;
            }
        }
    }
}

// ---------------- causal flash attention, v2.1 ----------------
// grid (32 bh, 8 pairs), 4 waves/block. Block processes q-tiles {p, 15-p} (128 rows each)
// sequentially -> exactly 34 kv-tiles per block (balanced). Each wave owns 32 q-rows.
// K [64][128] and Vt [128][64] staged into double-buffered LDS via global_load_lds
// (pre-swizzled source, XOR chunk^row&7). Swapped QK^T: mfma(K, Q) so each lane holds
// 16 scores for one q-row -> softmax = in-lane reduce + 2 shuffles. P via packed LDS.
// v2.1 fix: LDS double-buffer stride is 16384 B (64*128*2), NOT 32768 — R2's bug made
// buffer-1 K/V alias Vs[0]/Pl.
constexpr int KVBUF = 64 * 128 * (int)sizeof(bf16_t);  // 16384 bytes per buffer

__global__ __launch_bounds__(256) void attn(
    const bf16_t* __restrict__ Q, const bf16_t* __restrict__ Kc,
    const bf16_t* __restrict__ Vt, bf16_t* __restrict__ Ctx) {
    const int bh = blockIdx.x, b = bh >> 4, h = bh & 15;
    const int pr = blockIdx.y;
    const int lane = threadIdx.x & 63, wave = threadIdx.x >> 6;
    const int fr = lane & 15, fq = lane >> 4;

    __shared__ bf16_t Ks[2][64 * 128];
    __shared__ bf16_t Vs[2][128 * 64];
    __shared__ bf16_t Pl[4][32][72];

    const bf16_t* Kbase = Kc + (size_t)b * S_ * AF + h * DH;
    const bf16_t* Vbase = Vt + (size_t)bh * DH * S_;
    const float scale = 0.022097086912079608f;  // 1/sqrt(2048)
    const f32x4 fz = {0.f, 0.f, 0.f, 0.f};

    // staging: K tile rows 16*wave..+15 (4 rows per 1KB instr), V rows 32*wave..+31
    auto stage = [&](int buf, int kv0) {
#pragma unroll
        for (int i = 0; i < 4; ++i) {
            const int rt = wave * 16 + 4 * i + (lane >> 4);
            const bf16_t* src = Kbase + (size_t)(kv0 + rt) * AF + (((lane & 15) ^ (rt & 7)) << 3);
            gload16(src, (char*)Ks + buf * KVBUF + (wave * 16 + 4 * i) * 256);
        }
#pragma unroll
        for (int i = 0; i < 4; ++i) {
            const int rt = wave * 32 + 8 * i + (lane >> 3);
            const bf16_t* src = Vbase + (size_t)rt * S_ + kv0 + (((lane & 7) ^ (rt & 7)) << 3);
            gload16(src, (char*)Vs + buf * KVBUF + (wave * 32 + 8 * i) * 128);
        }
    };

    for (int ph = 0; ph < 2; ++ph) {
        const int qt = ph ? (15 - pr) : pr;
        const int q0 = qt * 128;
        const int NT = 2 * qt + 2;

        // Q fragments: wave rows q0 + wave*32 + qg*16 + fr
        bf16x8 qf[2][4];
#pragma unroll
        for (int qg = 0; qg < 2; ++qg) {
            const bf16_t* qp = Q + (size_t)(b * S_ + q0 + wave * 32 + qg * 16 + fr) * AF + h * DH + fq * 8;
#pragma unroll
            for (int ds = 0; ds < 4; ++ds) qf[qg][ds] = *reinterpret_cast<const bf16x8*>(qp + ds * 32);
        }
        float m_[2] = {-3.0e38f, -3.0e38f}, l_[2] = {0.f, 0.f};
        f32x4 o[2][8];
#pragma unroll
        for (int qg = 0; qg < 2; ++qg)
#pragma unroll
            for (int d = 0; d < 8; ++d) o[qg][d] = fz;

        __syncthreads();           // protect buffers from previous phase
        stage(0, 0);
        __syncthreads();           // drains vmcnt -> tile 0 ready

        for (int t = 0; t < NT; ++t) {
            const int cur = t & 1;
            if (t + 1 < NT) stage(cur ^ 1, (t + 1) * 64);
            const int kv0 = t * 64;
            const char* kb = (const char*)Ks + cur * KVBUF;
            const char* vb = (const char*)Vs + cur * KVBUF;

            // ---- QK^T (swapped: A=K rows, B=Q rows) ----
            f32x4 sv[2][4];
#pragma unroll
            for (int kvf = 0; kvf < 4; ++kvf) {
                bf16x8 kf[4];
#pragma unroll
                for (int ds = 0; ds < 4; ++ds) {
                    const int r = kvf * 16 + fr;
                    kf[ds] = *reinterpret_cast<const bf16x8*>(kb + r * 256 + ((ds * 64 + fq * 16) ^ ((r & 7) << 4)));
                }
                sv[0][kvf] = fz; sv[1][kvf] = fz;
#pragma unroll
                for (int ds = 0; ds < 4; ++ds) {
                    sv[0][kvf] = mfma16(kf[ds], qf[0][ds], sv[0][kvf]);
                    sv[1][kvf] = mfma16(kf[ds], qf[1][ds], sv[1][kvf]);
                }
            }
            const bool diag = (t >= 2 * qt);

            // ---- softmax (lane owns 16 scores of q = qg*16+fr) ----
#pragma unroll
            for (int qg = 0; qg < 2; ++qg) {
                const int q_abs = q0 + wave * 32 + qg * 16 + fr;
                float x[16], mx = -3.0e38f;
#pragma unroll
                for (int kvf = 0; kvf < 4; ++kvf)
#pragma unroll
                    for (int r = 0; r < 4; ++r) {
                        float tv = sv[qg][kvf][r] * scale;
                        if (diag && (kv0 + kvf * 16 + fq * 4 + r > q_abs)) tv = -3.0e38f;
                        x[kvf * 4 + r] = tv;
                        mx = fmaxf(mx, tv);
                    }
                mx = fmaxf(mx, __shfl_xor(mx, 16, 64));
                mx = fmaxf(mx, __shfl_xor(mx, 32, 64));
                const float mnew = fmaxf(m_[qg], mx);
                const float corr = __expf(m_[qg] - mnew);
                float rs = 0.f;
#pragma unroll
                for (int j = 0; j < 16; ++j) { x[j] = __expf(x[j] - mnew); rs += x[j]; }
                rs += __shfl_xor(rs, 16, 64);
                rs += __shfl_xor(rs, 32, 64);
                l_[qg] = l_[qg] * corr + rs;
                m_[qg] = mnew;
                // P -> LDS packed (row q = qg*16+fr, cols kvf*16+fq*4..+3)
#pragma unroll
                for (int kvf = 0; kvf < 4; ++kvf) {
                    bf16x4 pw = { (bf16_t)x[kvf * 4 + 0], (bf16_t)x[kvf * 4 + 1],
                                  (bf16_t)x[kvf * 4 + 2], (bf16_t)x[kvf * 4 + 3] };
                    *reinterpret_cast<bf16x4*>(&Pl[wave][qg * 16 + fr][kvf * 16 + fq * 4]) = pw;
                }
                // rescale o (o rows are q = fq*4+reg -> fetch corr cross-lane)
                float cr[4];
#pragma unroll
                for (int r = 0; r < 4; ++r) cr[r] = __shfl(corr, fq * 4 + r, 64);
#pragma unroll
                for (int d = 0; d < 8; ++d)
#pragma unroll
                    for (int r = 0; r < 4; ++r) o[qg][d][r] *= cr[r];
            }

            // ---- PV: A = P (rows q), B = Vt (rows d) ----
#pragma unroll
            for (int ks = 0; ks < 2; ++ks) {
                bf16x8 pa[2];
#pragma unroll
                for (int qg = 0; qg < 2; ++qg)
                    pa[qg] = *reinterpret_cast<const bf16x8*>(
                        reinterpret_cast<const char*>(&Pl[wave][qg * 16 + fr][0]) + ks * 64 + fq * 16);
#pragma unroll
                for (int d = 0; d < 8; ++d) {
                    const int rv = d * 16 + fr;
                    const bf16x8 vf = *reinterpret_cast<const bf16x8*>(
                        vb + rv * 128 + ((ks * 64 + fq * 16) ^ ((rv & 7) << 4)));
                    o[0][d] = mfma16(pa[0], vf, o[0][d]);
                    o[1][d] = mfma16(pa[1], vf, o[1][d]);
                }
            }
            __syncthreads();  // next tile staged & current reads done
        }

        // ---- epilogue ----
#pragma unroll
        for (int qg = 0; qg < 2; ++qg) {
            float li[4];
#pragma unroll
            for (int r = 0; r < 4; ++r) li[r] = 1.0f / __shfl(l_[qg], fq * 4 + r, 64);
#pragma unroll
            for (int d = 0; d < 8; ++d)
#pragma unroll
                for (int r = 0; r < 4; ++r) {
                    const size_t row = (size_t)(b * S_ + q0 + wave * 32 + qg * 16 + fq * 4 + r);
                    Ctx[row * AF + h * DH + d * 16 + fr] = (bf16_t)(o[qg][d][r] * li[r]);
                }
        }
    }
}

extern "C" void kernel_launch(void* const* d_in, const int* in_sizes, int n_in,
                              void* d_out, int out_size, void* d_ws, size_t ws_size,
                              hipStream_t stream) {
    const float* query = (const float*)d_in[0];
    const float* Wq = (const float*)d_in[1];
    const float* bq = (const float*)d_in[2];
    const float* Wk = (const float*)d_in[3];
    const float* bk = (const float*)d_in[4];
    const float* Wv = (const float*)d_in[5];
    const float* bv = (const float*)d_in[6];
    const float* Wo = (const float*)d_in[7];
    const float* bo = (const float*)d_in[8];
    float* out = (float*)d_out;
    char* ws = (char*)d_ws;

    bf16_t* xbf  = (bf16_t*)(ws + 0);
    bf16_t* wtq  = (bf16_t*)(ws + 8388608);
    bf16_t* wto  = (bf16_t*)(ws + 20971520);
    bf16_t* qws  = (bf16_t*)(ws + 25165824);
    bf16_t* vtws = (bf16_t*)(ws + 58720256);
    bf16_t* ctx  = (bf16_t*)(ws + 0);

    cvt_f32_to_bf16<<<4096, 256, 0, stream>>>(query, xbf);
    transpose_to_bf16<<<dim3(64, 32), 256, 0, stream>>>(Wq, wtq, 1024, 2048);
    transpose_to_bf16<<<dim3(64, 32), 256, 0, stream>>>(Wk, wtq + 2097152, 1024, 2048);
    transpose_to_bf16<<<dim3(64, 32), 256, 0, stream>>>(Wv, wtq + 2 * 2097152, 1024, 2048);
    transpose_to_bf16<<<dim3(32, 64), 256, 0, stream>>>(Wo, wto, 2048, 1024);

    gemm128<1024, 2048, true, true><<<dim3(16, 32, 3), 256, 0, stream>>>(
        xbf, wtq, bq, bk, bv, qws, vtws, nullptr);

    attn<<<dim3(32, 8), 256, 0, stream>>>(qws, qws + (size_t)4096 * 2048, vtws, ctx);

    gemm128<2048, 1024, false, false><<<dim3(8, 32, 1), 256, 0, stream>>>(
        ctx, wto, bo, bo, bo, nullptr, nullptr, out);
}

// Round 4
// 222.872 us; speedup vs baseline: 1.8865x; 1.0383x over previous
//
#include <hip/hip_runtime.h>

typedef __bf16 bf16_t;
typedef __bf16 bf16x8 __attribute__((ext_vector_type(8)));
typedef __bf16 bf16x4 __attribute__((ext_vector_type(4)));
typedef float f32x4 __attribute__((ext_vector_type(4)));

static __device__ __forceinline__ f32x4 mfma16(bf16x8 a, bf16x8 b, f32x4 c) {
    return __builtin_amdgcn_mfma_f32_16x16x32_bf16(a, b, c, 0, 0, 0);
}

#define AS1 __attribute__((address_space(1)))
#define AS3 __attribute__((address_space(3)))
static __device__ __forceinline__ void gload16(const void* g, void* l) {
    __builtin_amdgcn_global_load_lds((AS1 const void*)g, (AS3 void*)l, 16, 0, 0);
}

constexpr int B_ = 2, S_ = 2048, H_ = 16, DH = 128, AF = 2048;
constexpr int M_ = B_ * S_;  // 4096

// ---------------- f32 -> bf16 convert (query) ----------------
__global__ void cvt_f32_to_bf16(const float* __restrict__ in, bf16_t* __restrict__ out) {
    int i = (blockIdx.x * 256 + threadIdx.x) * 4;
    const float4 v = *reinterpret_cast<const float4*>(in + i);
    bf16x4 o = { (bf16_t)v.x, (bf16_t)v.y, (bf16_t)v.z, (bf16_t)v.w };
    *reinterpret_cast<bf16x4*>(out + i) = o;
}

// ---------------- f32 [R][C] -> bf16 [C][R] transpose ----------------
__global__ void transpose_to_bf16(const float* __restrict__ in, bf16_t* __restrict__ out,
                                  int R, int C) {
    __shared__ float t[32][33];
    int c0 = blockIdx.x * 32, r0 = blockIdx.y * 32;
    int tx = threadIdx.x & 31, ty = threadIdx.x >> 5;  // 32 x 8
#pragma unroll
    for (int i = 0; i < 4; i++) t[ty + i * 8][tx] = in[(size_t)(r0 + ty + i * 8) * C + c0 + tx];
    __syncthreads();
#pragma unroll
    for (int i = 0; i < 4; i++)
        out[(size_t)(c0 + ty + i * 8) * R + r0 + tx] = (bf16_t)t[tx][ty + i * 8];
}

// ---------------- 128x128-tile bf16 GEMM: C = A[M][K] * Bt[N][K]^T + bias ----------------
template <int K, int N, bool OUTBF16, bool QKV>
__global__ __launch_bounds__(256) void gemm128(
    const bf16_t* __restrict__ A, const bf16_t* __restrict__ Bt,
    const float* __restrict__ b0, const float* __restrict__ b1, const float* __restrict__ b2,
    bf16_t* __restrict__ Cqk, bf16_t* __restrict__ Vt, float* __restrict__ Cf) {
    __shared__ bf16_t As[128 * 64];
    __shared__ bf16_t Bs[128 * 64];
    const int z = blockIdx.z;
    const bf16_t* Bz = Bt + (size_t)z * N * K;
    const float* bias = (z == 0) ? b0 : (z == 1 ? b1 : b2);
    const int m0 = blockIdx.y * 128, n0 = blockIdx.x * 128;
    const int tid = threadIdx.x, lane = tid & 63, wave = tid >> 6;
    const int wm = (wave >> 1) * 64, wn = (wave & 1) * 64;
    const int fr = lane & 15, fq = lane >> 4;

    f32x4 acc[4][4];
    const f32x4 fz = {0.f, 0.f, 0.f, 0.f};
#pragma unroll
    for (int i = 0; i < 4; i++)
#pragma unroll
        for (int j = 0; j < 4; j++) acc[i][j] = fz;

    for (int kt = 0; kt < K / 64; ++kt) {
        const int k0 = kt * 64;
        bf16x8 ar[4], br[4];
#pragma unroll
        for (int j = 0; j < 4; j++) {
            int cid = tid + 256 * j;
            int r = cid >> 3;
            int sc = ((cid & 7) ^ (r & 7)) << 3;
            ar[j] = *reinterpret_cast<const bf16x8*>(A + (size_t)(m0 + r) * K + k0 + sc);
            br[j] = *reinterpret_cast<const bf16x8*>(Bz + (size_t)(n0 + r) * K + k0 + sc);
        }
#pragma unroll
        for (int j = 0; j < 4; j++) {
            int cid = tid + 256 * j;
            *reinterpret_cast<bf16x8*>(reinterpret_cast<char*>(As) + cid * 16) = ar[j];
            *reinterpret_cast<bf16x8*>(reinterpret_cast<char*>(Bs) + cid * 16) = br[j];
        }
        __syncthreads();
#pragma unroll
        for (int ks = 0; ks < 2; ++ks) {
            bf16x8 af[4], bfv[4];
#pragma unroll
            for (int mi = 0; mi < 4; mi++) {
                int r = wm + mi * 16 + fr;
                int cb = (ks * 64 + fq * 16) ^ ((r & 7) << 4);
                af[mi] = *reinterpret_cast<const bf16x8*>(reinterpret_cast<const char*>(As) + r * 128 + cb);
            }
#pragma unroll
            for (int ni = 0; ni < 4; ni++) {
                int r = wn + ni * 16 + fr;
                int cb = (ks * 64 + fq * 16) ^ ((r & 7) << 4);
                bfv[ni] = *reinterpret_cast<const bf16x8*>(reinterpret_cast<const char*>(Bs) + r * 128 + cb);
            }
#pragma unroll
            for (int mi = 0; mi < 4; mi++)
#pragma unroll
                for (int ni = 0; ni < 4; ni++) acc[mi][ni] = mfma16(af[mi], bfv[ni], acc[mi][ni]);
        }
        __syncthreads();
    }

#pragma unroll
    for (int ni = 0; ni < 4; ni++) {
        const int col = n0 + wn + ni * 16 + fr;
        const float bb = bias[col];
#pragma unroll
        for (int mi = 0; mi < 4; mi++) {
            const int mrow = m0 + wm + mi * 16 + fq * 4;
            f32x4 v = acc[mi][ni];
            if (OUTBF16) {
                if (QKV && z == 2) {
                    const int b = mrow >> 11, s = mrow & (S_ - 1);
                    const int h = col >> 7, d = col & (DH - 1);
                    bf16x4 w = { (bf16_t)(v[0] + bb), (bf16_t)(v[1] + bb),
                                 (bf16_t)(v[2] + bb), (bf16_t)(v[3] + bb) };
                    *reinterpret_cast<bf16x4*>(Vt + ((size_t)((b * H_ + h) * DH + d)) * S_ + s) = w;
                } else {
                    bf16_t* Cz = Cqk + (size_t)z * M_ * N;
#pragma unroll
                    for (int j = 0; j < 4; j++)
                        Cz[(size_t)(mrow + j) * N + col] = (bf16_t)(v[j] + bb);
                }
            } else {
#pragma unroll
                for (int j = 0; j < 4; j++) Cf[(size_t)(mrow + j) * N + col] = v[j] + bb;
            }
        }
    }
}

// ---------------- causal flash attention, v3 ----------------
// v3: occupancy fix. 512 one-q-tile blocks (128 q-rows each), LDS cut to exactly 80 KB
// (Pl XOR-swizzled [4][32][64], no pad) -> 2 blocks/CU, 2 waves/SIMD: one block's
// barrier/vmcnt drain hides under the other's compute. qt = (j<8 ? j : 23-j) makes
// blocks id and id+256 (same CU slot under round-robin) complementary: NT sums to 34.
// + defer-max (T13) and s_setprio around MFMA (T5).
constexpr int KVBUF = 64 * 128 * (int)sizeof(bf16_t);  // 16384 bytes per buffer

__global__ __launch_bounds__(256, 2) void attn(
    const bf16_t* __restrict__ Q, const bf16_t* __restrict__ Kc,
    const bf16_t* __restrict__ Vt, bf16_t* __restrict__ Ctx) {
    const int id = blockIdx.x;
    const int bh = id & 31, b = bh >> 4, h = bh & 15;
    const int j = id >> 5;
    const int qt = (j < 8) ? j : 23 - j;
    const int q0 = qt * 128;
    const int NT = 2 * qt + 2;
    const int lane = threadIdx.x & 63, wave = threadIdx.x >> 6;
    const int fr = lane & 15, fq = lane >> 4;

    __shared__ bf16_t Ks[2][64 * 128];   // 32 KB
    __shared__ bf16_t Vs[2][128 * 64];   // 32 KB
    __shared__ bf16_t Pl[4][32][64];     // 16 KB, XOR-swizzled (no pad)

    const bf16_t* Kbase = Kc + (size_t)b * S_ * AF + h * DH;
    const bf16_t* Vbase = Vt + (size_t)bh * DH * S_;
    const float scale = 0.022097086912079608f;  // 1/sqrt(2048)
    const f32x4 fz = {0.f, 0.f, 0.f, 0.f};

    auto stage = [&](int buf, int kv0) {
#pragma unroll
        for (int i = 0; i < 4; ++i) {
            const int rt = wave * 16 + 4 * i + (lane >> 4);
            const bf16_t* src = Kbase + (size_t)(kv0 + rt) * AF + (((lane & 15) ^ (rt & 7)) << 3);
            gload16(src, (char*)Ks + buf * KVBUF + (wave * 16 + 4 * i) * 256);
        }
#pragma unroll
        for (int i = 0; i < 4; ++i) {
            const int rt = wave * 32 + 8 * i + (lane >> 3);
            const bf16_t* src = Vbase + (size_t)rt * S_ + kv0 + (((lane & 7) ^ (rt & 7)) << 3);
            gload16(src, (char*)Vs + buf * KVBUF + (wave * 32 + 8 * i) * 128);
        }
    };

    // Q fragments: wave rows q0 + wave*32 + qg*16 + fr
    bf16x8 qf[2][4];
#pragma unroll
    for (int qg = 0; qg < 2; ++qg) {
        const bf16_t* qp = Q + (size_t)(b * S_ + q0 + wave * 32 + qg * 16 + fr) * AF + h * DH + fq * 8;
#pragma unroll
        for (int ds = 0; ds < 4; ++ds) qf[qg][ds] = *reinterpret_cast<const bf16x8*>(qp + ds * 32);
    }
    float m_[2] = {-3.0e38f, -3.0e38f}, l_[2] = {0.f, 0.f};
    f32x4 o[2][8];
#pragma unroll
    for (int qg = 0; qg < 2; ++qg)
#pragma unroll
        for (int d = 0; d < 8; ++d) o[qg][d] = fz;

    stage(0, 0);
    __syncthreads();  // drains vmcnt -> tile 0 ready

    char* PlB = reinterpret_cast<char*>(Pl) + wave * 32 * 128;

    for (int t = 0; t < NT; ++t) {
        const int cur = t & 1;
        if (t + 1 < NT) stage(cur ^ 1, (t + 1) * 64);
        const int kv0 = t * 64;
        const char* kb = (const char*)Ks + cur * KVBUF;
        const char* vb = (const char*)Vs + cur * KVBUF;

        // ---- QK^T (swapped: A=K rows, B=Q rows) -> sv[qg][kvf][r]: kv=kvf*16+fq*4+r, q=fr ----
        f32x4 sv[2][4];
        __builtin_amdgcn_s_setprio(1);
#pragma unroll
        for (int kvf = 0; kvf < 4; ++kvf) {
            bf16x8 kf[4];
#pragma unroll
            for (int ds = 0; ds < 4; ++ds) {
                const int r = kvf * 16 + fr;
                kf[ds] = *reinterpret_cast<const bf16x8*>(kb + r * 256 + ((ds * 64 + fq * 16) ^ ((r & 7) << 4)));
            }
            sv[0][kvf] = fz; sv[1][kvf] = fz;
#pragma unroll
            for (int ds = 0; ds < 4; ++ds) {
                sv[0][kvf] = mfma16(kf[ds], qf[0][ds], sv[0][kvf]);
                sv[1][kvf] = mfma16(kf[ds], qf[1][ds], sv[1][kvf]);
            }
        }
        __builtin_amdgcn_s_setprio(0);
        const bool diag = (t >= 2 * qt);

        // ---- softmax (lane owns 16 scores of q-row q0+wave*32+qg*16+fr) ----
#pragma unroll
        for (int qg = 0; qg < 2; ++qg) {
            const int q_abs = q0 + wave * 32 + qg * 16 + fr;
            float x[16], mx = -3.0e38f;
#pragma unroll
            for (int kvf = 0; kvf < 4; ++kvf)
#pragma unroll
                for (int r = 0; r < 4; ++r) {
                    float tv = sv[qg][kvf][r] * scale;
                    if (diag && (kv0 + kvf * 16 + fq * 4 + r > q_abs)) tv = -3.0e38f;
                    x[kvf * 4 + r] = tv;
                    mx = fmaxf(mx, tv);
                }
            mx = fmaxf(mx, __shfl_xor(mx, 16, 64));
            mx = fmaxf(mx, __shfl_xor(mx, 32, 64));
            float mnew = m_[qg];
            // defer-max (T13): rescale only when the tile max meaningfully exceeds m
            if (!__all(mx <= m_[qg] + 8.f)) {
                mnew = fmaxf(m_[qg], mx);
                const float corr = __expf(m_[qg] - mnew);
                l_[qg] *= corr;
                float cr[4];
#pragma unroll
                for (int r = 0; r < 4; ++r) cr[r] = __shfl(corr, fq * 4 + r, 64);
#pragma unroll
                for (int d = 0; d < 8; ++d)
#pragma unroll
                    for (int r = 0; r < 4; ++r) o[qg][d][r] *= cr[r];
                m_[qg] = mnew;
            }
            float rs = 0.f;
#pragma unroll
            for (int jj = 0; jj < 16; ++jj) { x[jj] = __expf(x[jj] - mnew); rs += x[jj]; }
            rs += __shfl_xor(rs, 16, 64);
            rs += __shfl_xor(rs, 32, 64);
            l_[qg] += rs;
            // P -> LDS, XOR-swizzled row of 128 B: physical byte = logical ^ ((fr&7)<<4)
#pragma unroll
            for (int kvf = 0; kvf < 4; ++kvf) {
                bf16x4 pw = { (bf16_t)x[kvf * 4 + 0], (bf16_t)x[kvf * 4 + 1],
                              (bf16_t)x[kvf * 4 + 2], (bf16_t)x[kvf * 4 + 3] };
                *reinterpret_cast<bf16x4*>(
                    PlB + (qg * 16 + fr) * 128 + ((kvf * 32 + fq * 8) ^ ((fr & 7) << 4))) = pw;
            }
        }

        // ---- PV: A = P (rows q), B = Vt (rows d) ----
#pragma unroll
        for (int ks = 0; ks < 2; ++ks) {
            bf16x8 pa[2];
#pragma unroll
            for (int qg = 0; qg < 2; ++qg)
                pa[qg] = *reinterpret_cast<const bf16x8*>(
                    PlB + (qg * 16 + fr) * 128 + ((ks * 64 + fq * 16) ^ ((fr & 7) << 4)));
            __builtin_amdgcn_s_setprio(1);
#pragma unroll
            for (int d = 0; d < 8; ++d) {
                const int rv = d * 16 + fr;
                const bf16x8 vf = *reinterpret_cast<const bf16x8*>(
                    vb + rv * 128 + ((ks * 64 + fq * 16) ^ ((rv & 7) << 4)));
                o[0][d] = mfma16(pa[0], vf, o[0][d]);
                o[1][d] = mfma16(pa[1], vf, o[1][d]);
            }
            __builtin_amdgcn_s_setprio(0);
        }
        __syncthreads();  // next tile staged & current reads done
    }

    // ---- epilogue ----
#pragma unroll
    for (int qg = 0; qg < 2; ++qg) {
        float li[4];
#pragma unroll
        for (int r = 0; r < 4; ++r) li[r] = 1.0f / __shfl(l_[qg], fq * 4 + r, 64);
#pragma unroll
        for (int d = 0; d < 8; ++d)
#pragma unroll
            for (int r = 0; r < 4; ++r) {
                const size_t row = (size_t)(b * S_ + q0 + wave * 32 + qg * 16 + fq * 4 + r);
                Ctx[row * AF + h * DH + d * 16 + fr] = (bf16_t)(o[qg][d][r] * li[r]);
            }
    }
}

extern "C" void kernel_launch(void* const* d_in, const int* in_sizes, int n_in,
                              void* d_out, int out_size, void* d_ws, size_t ws_size,
                              hipStream_t stream) {
    const float* query = (const float*)d_in[0];
    const float* Wq = (const float*)d_in[1];
    const float* bq = (const float*)d_in[2];
    const float* Wk = (const float*)d_in[3];
    const float* bk = (const float*)d_in[4];
    const float* Wv = (const float*)d_in[5];
    const float* bv = (const float*)d_in[6];
    const float* Wo = (const float*)d_in[7];
    const float* bo = (const float*)d_in[8];
    float* out = (float*)d_out;
    char* ws = (char*)d_ws;

    bf16_t* xbf  = (bf16_t*)(ws + 0);
    bf16_t* wtq  = (bf16_t*)(ws + 8388608);
    bf16_t* wto  = (bf16_t*)(ws + 20971520);
    bf16_t* qws  = (bf16_t*)(ws + 25165824);
    bf16_t* vtws = (bf16_t*)(ws + 58720256);
    bf16_t* ctx  = (bf16_t*)(ws + 0);

    cvt_f32_to_bf16<<<4096, 256, 0, stream>>>(query, xbf);
    transpose_to_bf16<<<dim3(64, 32), 256, 0, stream>>>(Wq, wtq, 1024, 2048);
    transpose_to_bf16<<<dim3(64, 32), 256, 0, stream>>>(Wk, wtq + 2097152, 1024, 2048);
    transpose_to_bf16<<<dim3(64, 32), 256, 0, stream>>>(Wv, wtq + 2 * 2097152, 1024, 2048);
    transpose_to_bf16<<<dim3(32, 64), 256, 0, stream>>>(Wo, wto, 2048, 1024);

    gemm128<1024, 2048, true, true><<<dim3(16, 32, 3), 256, 0, stream>>>(
        xbf, wtq, bq, bk, bv, qws, vtws, nullptr);

    attn<<<512, 256, 0, stream>>>(qws, qws + (size_t)4096 * 2048, vtws, ctx);

    gemm128<2048, 1024, false, false><<<dim3(8, 32, 1), 256, 0, stream>>>(
        ctx, wto, bo, bo, bo, nullptr, nullptr, out);
}